// Round 4
// baseline (417.524 us; speedup 1.0000x reference)
//
#include <hip/hip_runtime.h>

// ---------------- constants (match reference) ----------------
// B,H,W,F,D = 8,126,126,64,32 ; grid fields are (8,128,128,32)
#define NITER 20
#define OUTER 3

constexpr double DXd  = 2.0 / 9.0;     // 2/(B+1)
constexpr double DYd  = 2.0 / 127.0;   // 2/(H+1)
constexpr double DX2d = DXd * DXd;
constexpr double DY2d = DYd * DYd;
constexpr double DENd = 2.0 * (DX2d + DY2d);

constexpr float K1     = (float)(DY2d / DENd);          // * (E+W)
constexpr float K2     = (float)(DX2d / DENd);          // * (N+S)
constexpr float CC     = (float)(DX2d * DY2d / DENd);   // c coefficient
constexpr float INV2DX = (float)(1.0 / (2.0 * DXd));
constexpr float INV2DY = (float)(1.0 / (2.0 * DYd));
constexpr float INVDT  = 10.0f;                          // 1/DT
constexpr float DTDX   = (float)(0.1 / DXd);
constexpr float DTDY   = (float)(0.1 / DYd);
constexpr float PGX    = (float)(0.1 / (2.0 * DXd));     // DT/(2 RHO DX)
constexpr float PGY    = (float)(0.1 / (2.0 * DYd));
constexpr float A1     = (float)(0.1 / DX2d);            // DT/DX2
constexpr float A2     = (float)(0.1 / DY2d);            // DT/DY2
constexpr float NUf    = 0.1f;
constexpr float FDT    = 0.1f;                           // FRC*DT

__device__ __forceinline__ float bperm(int srcByte, float v) {
    return __int_as_float(__builtin_amdgcn_ds_bpermute(srcByte, __float_as_int(v)));
}

// DPP row_shr prefix adds (VALU-only 16-lane reduction; bound_ctrl=1 -> 0-fill)
__device__ __forceinline__ float dpp_add1(float s) {
    return s + __int_as_float(__builtin_amdgcn_update_dpp(0, __float_as_int(s), 0x111, 0xF, 0xF, true));
}
__device__ __forceinline__ float dpp_add2(float s) {
    return s + __int_as_float(__builtin_amdgcn_update_dpp(0, __float_as_int(s), 0x112, 0xF, 0xF, true));
}
__device__ __forceinline__ float dpp_add4(float s) {
    return s + __int_as_float(__builtin_amdgcn_update_dpp(0, __float_as_int(s), 0x114, 0xF, 0xF, true));
}
__device__ __forceinline__ float dpp_add8(float s) {
    return s + __int_as_float(__builtin_amdgcn_update_dpp(0, __float_as_int(s), 0x118, 0xF, 0xF, true));
}

struct SimShared {
    float sP[2][16][4][128];   // ping-pong p seams: [0]=row0,[1]=row1,[2]=row6,[3]=row7 per ty
    float sU[16][2][128];      // u seams: row0,row7
    float sV[16][2][128];
    float sCB[16][2][128];     // cb seams: row0,row7 (per outer)
};

// ---------------- one workgroup per (b,d) plane; 512 thr = 32 tx (4 cols) x 16 ty (8 rows)
__global__ __launch_bounds__(512, 2) void sim_kernel(
    const float* __restrict__ u0, const float* __restrict__ v0,
    const float* __restrict__ x,  const float* __restrict__ w,
    const float* __restrict__ bl, float* __restrict__ out)
{
    __shared__ union ShU {
        SimShared s;          // 112 KB
        float pFull[16384];   // 64 KB, used only during init
    } shm;

    const int tid = threadIdx.x;
    const int tx = tid & 31, ty = tid >> 5;
    const int c0 = tx << 2, r0 = ty << 3;
    const int lane = tid & 63;
    const int wvid = tid >> 6;
    const int srcL = (((lane & 32) | ((lane + 31) & 31)) << 2); // lane of tx-1 (periodic)
    const int srcR = (((lane & 32) | ((lane + 1) & 31)) << 2);  // lane of tx+1
    const int bb = blockIdx.x & 7;   // batch (XCD pinning: x[bb] resident in one XCD's L2)
    const int d  = blockIdx.x >> 3;  // channel

    float pC[8][4], uC[8][4], vC[8][4], cb[8][4];

    // ======== einsum p0: lanes = 4 cells x 16 f-chunks; coalesced 1KB loads ========
    {
        const float4 wq = *(const float4*)(w + d * 64 + (lane & 15) * 4);
        const float* xb = x + (size_t)bb * (126 * 126 * 64);
        for (int g = wvid; g < 3969; g += 8) {          // 15876 interior cells / 4
            float4 xv = *(const float4*)(xb + g * 256 + lane * 4);
            float pa = xv.x * wq.x + xv.y * wq.y + xv.z * wq.z + xv.w * wq.w;
            pa = dpp_add1(pa); pa = dpp_add2(pa); pa = dpp_add4(pa); pa = dpp_add8(pa);
            if ((lane & 15) == 15) {                    // lanes 15/31/47/63 hold cell sums
                int ci = g * 4 + (lane >> 4);           // cell = rr*126+cc
                int rr = (int)((unsigned)ci / 126u);
                shm.pFull[ci + 2 * rr + 129] = pa;      // (rr+1)*128 + (cc+1)
            }
        }
    }
    __syncthreads();
    // owners gather p0 (edge cells = bias only; garbage LDS words cndmask'd away)
    {
        const float blv = bl[d];
#pragma unroll
        for (int r = 0; r < 8; ++r) {
            const int gr = r0 + r;
            float4 t = *(const float4*)&shm.pFull[gr * 128 + c0];
            float vals[4] = {t.x, t.y, t.z, t.w};
#pragma unroll
            for (int c = 0; c < 4; ++c) {
                const int gc = c0 + c;
                bool inter = (gr >= 1) && (gr <= 126) && (gc >= 1) && (gc <= 126);
                pC[r][c] = inter ? vals[c] + blv : blv;
            }
        }
    }
    __syncthreads();   // all pFull reads done before arena is reused as seams

    // ---- load u, v ----
#pragma unroll
    for (int r = 0; r < 8; ++r) {
        const size_t base = ((size_t)((bb * 128 + (r0 + r)) * 128 + c0)) * 32 + d;
#pragma unroll
        for (int c = 0; c < 4; ++c) {
            uC[r][c] = u0[base + (size_t)c * 32];
            vC[r][c] = v0[base + (size_t)c * 32];
        }
    }

    // ---- initial seams ----
    int s = 0;
    *(float4*)&shm.s.sP[0][ty][0][c0] = make_float4(pC[0][0], pC[0][1], pC[0][2], pC[0][3]);
    *(float4*)&shm.s.sP[0][ty][1][c0] = make_float4(pC[1][0], pC[1][1], pC[1][2], pC[1][3]);
    *(float4*)&shm.s.sP[0][ty][2][c0] = make_float4(pC[6][0], pC[6][1], pC[6][2], pC[6][3]);
    *(float4*)&shm.s.sP[0][ty][3][c0] = make_float4(pC[7][0], pC[7][1], pC[7][2], pC[7][3]);
    *(float4*)&shm.s.sU[ty][0][c0]    = make_float4(uC[0][0], uC[0][1], uC[0][2], uC[0][3]);
    *(float4*)&shm.s.sU[ty][1][c0]    = make_float4(uC[7][0], uC[7][1], uC[7][2], uC[7][3]);
    *(float4*)&shm.s.sV[ty][0][c0]    = make_float4(vC[0][0], vC[0][1], vC[0][2], vC[0][3]);
    *(float4*)&shm.s.sV[ty][1][c0]    = make_float4(vC[7][0], vC[7][1], vC[7][2], vC[7][3]);
    __syncthreads();

    const int tyN = (ty > 0) ? ty - 1 : 0;    // clamped: edge garbage is finite + discarded
    const int tyS = (ty < 15) ? ty + 1 : 15;

    for (int outer = 0; outer < OUTER; ++outer) {
        // ================= build_b -> cb = -(CC * b) =================
        {
            float4 uN4 = *(const float4*)&shm.s.sU[tyN][1][c0];
            float4 uS4 = *(const float4*)&shm.s.sU[tyS][0][c0];
            float4 vN4 = *(const float4*)&shm.s.sV[tyN][1][c0];
            float4 vS4 = *(const float4*)&shm.s.sV[tyS][0][c0];
            float uNh[4] = {uN4.x, uN4.y, uN4.z, uN4.w};
            float uSh[4] = {uS4.x, uS4.y, uS4.z, uS4.w};
            float vNh[4] = {vN4.x, vN4.y, vN4.z, vN4.w};
            float vSh[4] = {vS4.x, vS4.y, vS4.z, vS4.w};
#pragma unroll
            for (int r = 0; r < 8; ++r) {
                float uWh = bperm(srcL, uC[r][3]);
                float uEh = bperm(srcR, uC[r][0]);
                float vWh = bperm(srcL, vC[r][3]);
                float vEh = bperm(srcR, vC[r][0]);
#pragma unroll
                for (int c = 0; c < 4; ++c) {
                    float uE = (c < 3) ? uC[r][c + 1] : uEh;
                    float uW = (c > 0) ? uC[r][c - 1] : uWh;
                    float vE = (c < 3) ? vC[r][c + 1] : vEh;
                    float vW = (c > 0) ? vC[r][c - 1] : vWh;
                    float uN = (r > 0) ? uC[r - 1][c] : uNh[c];
                    float uS = (r < 7) ? uC[r + 1][c] : uSh[c];
                    float vN = (r > 0) ? vC[r - 1][c] : vNh[c];
                    float vS = (r < 7) ? vC[r + 1][c] : vSh[c];
                    float dudx = (uE - uW) * INV2DX;
                    float dvdy = (vS - vN) * INV2DY;
                    float dudy = (uS - uN) * INV2DY;
                    float dvdx = (vE - vW) * INV2DX;
                    float bt = (dudx + dvdy) * INVDT - dudx * dudx
                             - 2.0f * dudy * dvdx - dvdy * dvdy;   // RHO == 1
                    cb[r][c] = -(CC * bt);
                }
            }
        }
        // publish cb seam rows (constant across the 20 Jacobi iterations)
        *(float4*)&shm.s.sCB[ty][0][c0] = make_float4(cb[0][0], cb[0][1], cb[0][2], cb[0][3]);
        *(float4*)&shm.s.sCB[ty][1][c0] = make_float4(cb[7][0], cb[7][1], cb[7][2], cb[7][3]);
        __syncthreads();
        float cbN[4], cbS[4];
        {
            float4 a = *(const float4*)&shm.s.sCB[tyN][1][c0];
            float4 b = *(const float4*)&shm.s.sCB[tyS][0][c0];
            cbN[0]=a.x; cbN[1]=a.y; cbN[2]=a.z; cbN[3]=a.w;
            cbS[0]=b.x; cbS[1]=b.y; cbS[2]=b.z; cbS[3]=b.w;
        }

        // ================= pressure_poisson: 20 iters as 10 two-step periods ========
        for (int per = 0; per < NITER / 2; ++per) {
            float hN0[4], hN1[4], hS0[4], hS1[4];   // old rows r0-2, r0-1, r0+8, r0+9
            {
                float4 a = *(const float4*)&shm.s.sP[s][tyN][2][c0];
                float4 b = *(const float4*)&shm.s.sP[s][tyN][3][c0];
                float4 e = *(const float4*)&shm.s.sP[s][tyS][0][c0];
                float4 f = *(const float4*)&shm.s.sP[s][tyS][1][c0];
                hN0[0]=a.x; hN0[1]=a.y; hN0[2]=a.z; hN0[3]=a.w;
                hN1[0]=b.x; hN1[1]=b.y; hN1[2]=b.z; hN1[3]=b.w;
                hS0[0]=e.x; hS0[1]=e.y; hS0[2]=e.z; hS0[3]=e.w;
                hS1[0]=f.x; hS1[1]=f.y; hS1[2]=f.z; hS1[3]=f.w;
            }
            // old-row accessor: O[j], j=0..11 -> grid row r0-2+j
            auto ORow = [&](int j) -> const float* {
                if (j == 0)  return hN0;
                if (j == 1)  return hN1;
                if (j == 10) return hS0;
                if (j == 11) return hS1;
                return pC[j - 2];
            };
            // E/W halos of ALL old rows used by step A (issued before any overwrite)
            float oW[10], oE[10];
#pragma unroll
            for (int k = 0; k < 10; ++k) {
                const float* Or = ORow(k + 1);
                oW[k] = bperm(srcL, Or[3]);
                oE[k] = bperm(srcR, Or[0]);
            }
            float A[10][4];   // A[k] = step-1 value at grid row r0-1+k
            auto computeA = [&](int k) {
                const float* Oc = ORow(k + 1);
                const float* Nr = ORow(k);
                const float* Sr = ORow(k + 2);
                const float* cbk = (k == 0) ? cbN : (k == 9) ? cbS : cb[k - 1];
#pragma unroll
                for (int c = 0; c < 4; ++c) {
                    float E = (c < 3) ? Oc[c + 1] : oE[k];
                    float W = (c > 0) ? Oc[c - 1] : oW[k];
                    A[k][c] = (E + W) * K1 + ((Nr[c] + Sr[c]) * K2 + cbk[c]);
                }
            };
            // step-2 row r (grid r0+r) from A[r..r+2]; overwrites pC[r]
            auto computeB = [&](int r) {
                float aW = bperm(srcL, A[r + 1][3]);
                float aE = bperm(srcR, A[r + 1][0]);
#pragma unroll
                for (int c = 0; c < 4; ++c) {
                    float E = (c < 3) ? A[r + 1][c + 1] : aE;
                    float W = (c > 0) ? A[r + 1][c - 1] : aW;
                    pC[r][c] = (E + W) * K1 + ((A[r][c] + A[r + 2][c]) * K2 + cb[r][c]);
                }
            };
            computeA(0); computeA(1); computeA(2);
            if (ty == 0) {      // grid row 0 BC after step 1: row0 = row1 (new)
#pragma unroll
                for (int c = 0; c < 4; ++c) A[1][c] = A[2][c];
            }
            computeB(0); computeA(3);
            computeB(1); computeA(4);
            computeB(2); computeA(5);
            computeB(3); computeA(6);
            computeB(4); computeA(7);
            computeB(5); computeA(8);
            if (ty == 15) {     // grid row 127 BC after step 1: row127 = row126 (new)
#pragma unroll
                for (int c = 0; c < 4; ++c) A[8][c] = A[7][c];
            }
            computeB(6); computeA(9);
            computeB(7);
            // step-2 row BCs
            if (ty == 0) {
#pragma unroll
                for (int c = 0; c < 4; ++c) pC[0][c] = pC[1][c];
            }
            if (ty == 15) {
#pragma unroll
                for (int c = 0; c < 4; ++c) pC[7][c] = pC[6][c];
            }
            // publish rows 0,1,6,7 into the other buffer; single barrier per 2 iters
            *(float4*)&shm.s.sP[s ^ 1][ty][0][c0] = make_float4(pC[0][0], pC[0][1], pC[0][2], pC[0][3]);
            *(float4*)&shm.s.sP[s ^ 1][ty][1][c0] = make_float4(pC[1][0], pC[1][1], pC[1][2], pC[1][3]);
            *(float4*)&shm.s.sP[s ^ 1][ty][2][c0] = make_float4(pC[6][0], pC[6][1], pC[6][2], pC[6][3]);
            *(float4*)&shm.s.sP[s ^ 1][ty][3][c0] = make_float4(pC[7][0], pC[7][1], pC[7][2], pC[7][3]);
            __syncthreads();
            s ^= 1;
        }

        // ================= velocity_step =================
        {
            float4 ut4 = *(const float4*)&shm.s.sU[tyN][1][c0];
            float4 us4 = *(const float4*)&shm.s.sU[tyS][0][c0];
            float4 vt4 = *(const float4*)&shm.s.sV[tyN][1][c0];
            float4 vs4 = *(const float4*)&shm.s.sV[tyS][0][c0];
            float4 pt4 = *(const float4*)&shm.s.sP[s][tyN][3][c0];
            float4 pb4 = *(const float4*)&shm.s.sP[s][tyS][0][c0];
            float uNh[4] = {ut4.x, ut4.y, ut4.z, ut4.w};
            float uSh[4] = {us4.x, us4.y, us4.z, us4.w};
            float vNh[4] = {vt4.x, vt4.y, vt4.z, vt4.w};
            float vSh[4] = {vs4.x, vs4.y, vs4.z, vs4.w};
            float pNh[4] = {pt4.x, pt4.y, pt4.z, pt4.w};
            float pSh[4] = {pb4.x, pb4.y, pb4.z, pb4.w};
            __syncthreads();   // all seam reads done before the sU/sV rewrites below

            float uNrow[4], vNrow[4];
#pragma unroll
            for (int c = 0; c < 4; ++c) { uNrow[c] = uNh[c]; vNrow[c] = vNh[c]; }
#pragma unroll
            for (int r = 0; r < 8; ++r) {
                float uold[4], vold[4];  // snapshot: same-row W neighbors must be OLD
#pragma unroll
                for (int c = 0; c < 4; ++c) { uold[c] = uC[r][c]; vold[c] = vC[r][c]; }
                float uWh = bperm(srcL, uold[3]);
                float uEh = bperm(srcR, uold[0]);
                float vWh = bperm(srcL, vold[3]);
                float vEh = bperm(srcR, vold[0]);
                float pWh = bperm(srcL, pC[r][3]);
                float pEh = bperm(srcR, pC[r][0]);
#pragma unroll
                for (int c = 0; c < 4; ++c) {
                    float uc = uold[c], vc = vold[c];
                    float uE = (c < 3) ? uold[c + 1] : uEh;
                    float uW = (c > 0) ? uold[c - 1] : uWh;
                    float vE = (c < 3) ? vold[c + 1] : vEh;
                    float vW = (c > 0) ? vold[c - 1] : vWh;
                    float uN = uNrow[c];
                    float uS = (r < 7) ? uC[r + 1][c] : uSh[c];
                    float vN = vNrow[c];
                    float vS = (r < 7) ? vC[r + 1][c] : vSh[c];
                    float pE = (c < 3) ? pC[r][c + 1] : pEh;
                    float pW = (c > 0) ? pC[r][c - 1] : pWh;
                    float pN = (r > 0) ? pC[r - 1][c] : pNh[c];
                    float pS = (r < 7) ? pC[r + 1][c] : pSh[c];

                    float unew = uc - uc * DTDX * (uc - uW) - vc * DTDY * (uc - uN)
                               - PGX * (pE - pW)
                               + NUf * (A1 * (uE - 2.0f * uc + uW) + A2 * (uS - 2.0f * uc + uN))
                               + FDT;
                    float vnew = vc - uc * DTDX * (vc - vW) - vc * DTDY * (vc - vN)
                               - PGY * (pS - pN)
                               + NUf * (A1 * (vE - 2.0f * vc + vW) + A2 * (vS - 2.0f * vc + vN));
                    uC[r][c] = unew;
                    vC[r][c] = vnew;
                }
#pragma unroll
                for (int c = 0; c < 4; ++c) { uNrow[c] = uold[c]; vNrow[c] = vold[c]; }
            }
            // u,v row BCs: rows 0 and 127 -> 0 (repairs discarded edge rows)
            if (ty == 0) {
#pragma unroll
                for (int c = 0; c < 4; ++c) { uC[0][c] = 0.0f; vC[0][c] = 0.0f; }
            }
            if (ty == 15) {
#pragma unroll
                for (int c = 0; c < 4; ++c) { uC[7][c] = 0.0f; vC[7][c] = 0.0f; }
            }
            *(float4*)&shm.s.sU[ty][0][c0] = make_float4(uC[0][0], uC[0][1], uC[0][2], uC[0][3]);
            *(float4*)&shm.s.sU[ty][1][c0] = make_float4(uC[7][0], uC[7][1], uC[7][2], uC[7][3]);
            *(float4*)&shm.s.sV[ty][0][c0] = make_float4(vC[0][0], vC[0][1], vC[0][2], vC[0][3]);
            *(float4*)&shm.s.sV[ty][1][c0] = make_float4(vC[7][0], vC[7][1], vC[7][2], vC[7][3]);
            __syncthreads();
        }
    }

    // ---- output: p[:, row 127, :, :]  -> out[b][col][d] ----
    if (ty == 15) {
        float* op = out + ((size_t)bb * 128 + c0) * 32 + d;
        op[0]  = pC[7][0];
        op[32] = pC[7][1];
        op[64] = pC[7][2];
        op[96] = pC[7][3];
    }
}

extern "C" void kernel_launch(void* const* d_in, const int* in_sizes, int n_in,
                              void* d_out, int out_size, void* d_ws, size_t ws_size,
                              hipStream_t stream) {
    const float* x  = (const float*)d_in[0];
    const float* u0 = (const float*)d_in[1];
    const float* v0 = (const float*)d_in[2];
    const float* w  = (const float*)d_in[3];
    const float* bl = (const float*)d_in[4];
    float* out = (float*)d_out;
    (void)d_ws; (void)ws_size;

    sim_kernel<<<256, 512, 0, stream>>>(u0, v0, x, w, bl, out);
}